// Round 1
// baseline (5969.993 us; speedup 1.0000x reference)
//
#include <hip/hip_runtime.h>
#include <hip/hip_bf16.h>

#define NB 4
#define NT 16
#define ND 64
#define NHW 4096
#define NTOT (NB*NT*ND*NHW)   // 16,777,216 per plane

// ---------------------------------------------------------------- spec reorder
// out[d][r][c] = in[d][bitrev6(r)][bitrev6(c)]
__global__ void k_spec_reorder(const float* __restrict__ wr, const float* __restrict__ wi,
                               float* __restrict__ outr, float* __restrict__ outi) {
  int idx = blockIdx.x * 256 + threadIdx.x;      // D*HW = 262144
  int d = idx >> 12;
  int rc = idx & 4095;
  int r = rc >> 6, c = rc & 63;
  int br = __brev((unsigned)r) >> 26;
  int bc = __brev((unsigned)c) >> 26;
  int src = (d << 12) + (br << 6) + bc;
  outr[idx] = wr[src];
  outi[idx] = wi[src];
}

// ---------------------------------------------------------------- complex LN
// per (bt,h,w): LN over concat[real(d=0..63), imag(d=0..63)]
__global__ void k_ln(const float* __restrict__ xr, const float* __restrict__ xi,
                     const float* __restrict__ g, const float* __restrict__ b,
                     float* __restrict__ outr, float* __restrict__ outi) {
  int pos = blockIdx.x * 256 + threadIdx.x;      // B*T*HW = 262144
  int bt = pos >> 12;
  int hw = pos & 4095;
  size_t base = (size_t)bt * ND * NHW + hw;
  float s = 0.f, ss = 0.f;
  for (int d = 0; d < ND; ++d) {
    float r = xr[base + (size_t)d * NHW];
    float im = xi[base + (size_t)d * NHW];
    s += r + im; ss += r * r + im * im;
  }
  float mean = s * (1.0f / 128.0f);
  float var = ss * (1.0f / 128.0f) - mean * mean;
  float rstd = rsqrtf(var + 1e-5f);
  for (int d = 0; d < ND; ++d) {
    float r = xr[base + (size_t)d * NHW];
    float im = xi[base + (size_t)d * NHW];
    outr[base + (size_t)d * NHW] = (r - mean) * rstd * g[d] + b[d];
    outi[base + (size_t)d * NHW] = (im - mean) * rstd * g[64 + d] + b[64 + d];
  }
}

// ---------------------------------------------------------------- 3x3 conv
// in channels: 0..63 = xsr, 64..127 = xsi.  out: 0..63 -> cr, 64..127 -> ci (bf16)
// block: 256 thr, tile 16x32 (2 px/thread), 16 oc per block.
__global__ __launch_bounds__(256) void k_conv(
    const float* __restrict__ xsr, const float* __restrict__ xsi,
    const float* __restrict__ w, const float* __restrict__ bias,
    __hip_bfloat16* __restrict__ cr, __hip_bfloat16* __restrict__ ci) {
  __shared__ float tin[18 * 34];
  __shared__ float tw2[9 * 16];     // [k][o]
  int blk = blockIdx.x;             // bt*64 + ocg*8 + tile
  int tile = blk & 7;               // ty 0..3, tx 0..1
  int ocg = (blk >> 3) & 7;
  int bt = blk >> 6;
  int ty0 = (tile >> 1) * 16, tx0 = (tile & 1) * 32;
  int tid = threadIdx.x;
  int px = tid & 15, py = tid >> 4;
  float acc0[16], acc1[16];
#pragma unroll
  for (int o = 0; o < 16; ++o) { float bz = bias[ocg * 16 + o]; acc0[o] = bz; acc1[o] = bz; }
  for (int ic = 0; ic < 128; ++ic) {
    const float* src = (ic < 64) ? xsr : xsi;
    size_t sb = ((size_t)(bt * 64 + (ic & 63))) * NHW;
    for (int i = tid; i < 612; i += 256) {
      int iy = i / 34, ix = i - iy * 34;
      int gy = ty0 + iy - 1, gx = tx0 + ix - 1;
      float v = 0.0f;
      if (gy >= 0 && gy < 64 && gx >= 0 && gx < 64) v = src[sb + gy * 64 + gx];
      tin[i] = v;
    }
    if (tid < 144) {
      int o = tid / 9, kk = tid - o * 9;
      tw2[kk * 16 + o] = w[((size_t)(ocg * 16 + o) * 128 + ic) * 9 + kk];
    }
    __syncthreads();
#pragma unroll
    for (int ky = 0; ky < 3; ++ky) {
#pragma unroll
      for (int kx = 0; kx < 3; ++kx) {
        float v0 = tin[(py + ky) * 34 + px + kx];
        float v1 = tin[(py + ky) * 34 + px + 16 + kx];
        int kk = ky * 3 + kx;
#pragma unroll
        for (int o = 0; o < 16; ++o) {
          float wv = tw2[kk * 16 + o];
          acc0[o] += v0 * wv; acc1[o] += v1 * wv;
        }
      }
    }
    __syncthreads();
  }
  int oc0 = ocg * 16;
#pragma unroll
  for (int o = 0; o < 16; ++o) {
    int oc = oc0 + o;
    __hip_bfloat16* dst = (oc < 64) ? cr : ci;
    size_t ob = ((size_t)(bt * 64 + (oc & 63))) * NHW + (ty0 + py) * 64 + tx0;
    dst[ob + px] = __float2bfloat16(acc0[o]);
    dst[ob + px + 16] = __float2bfloat16(acc1[o]);
  }
}

// ---------------------------------------------------------------- FFT64 via shfl
__device__ __forceinline__ void fft64_fwd(float& re, float& im, int lane) {
#pragma unroll
  for (int m = 32; m >= 1; m >>= 1) {
    float pr = __shfl_xor(re, m, 64);
    float pi = __shfl_xor(im, m, 64);
    int j = lane & (m - 1);
    float ang = -3.14159265358979f * (float)j / (float)m;   // W = e^{-2*pi*i*j/(2m)}
    float s, c;
    __sincosf(ang, &s, &c);
    if (lane & m) {
      float tr = pr - re, ti = pi - im;
      re = tr * c - ti * s;
      im = tr * s + ti * c;
    } else { re += pr; im += pi; }
  }
}
__device__ __forceinline__ void fft64_inv(float& re, float& im, int lane) {
#pragma unroll
  for (int m = 1; m <= 32; m <<= 1) {
    int j = lane & (m - 1);
    float ang = 3.14159265358979f * (float)j / (float)m;    // conj twiddle
    float s, c;
    __sincosf(ang, &s, &c);
    float pr = __shfl_xor(re, m, 64);
    float pi = __shfl_xor(im, m, 64);
    if (lane & m) {
      float wr = re * c - im * s, wi = re * s + im * c;
      re = pr - wr; im = pi - wi;
    } else {
      float wr = pr * c - pi * s, wi = pr * s + pi * c;
      re += wr; im += wi;
    }
  }
}

// fft2 -> *spec -> ifft2, then x = gate*cliff + (1-gate)*spec + x_orig (in-place into xs)
__global__ __launch_bounds__(256) void k_fft_combine(
    float* xsr, float* xsi,
    const __hip_bfloat16* __restrict__ cr, const __hip_bfloat16* __restrict__ ci,
    const float* __restrict__ sbr, const float* __restrict__ sbi,
    const float* __restrict__ x0r, const float* __restrict__ x0i,
    const float* __restrict__ gate) {
  __shared__ float lr[64 * 65], li[64 * 65];
  int slice = blockIdx.x;                      // bt*64 + d
  int d = slice & 63;
  size_t base = (size_t)slice * NHW;
  int lane = threadIdx.x & 63, wv = threadIdx.x >> 6;
  float g = gate[0];
  // rows forward
  for (int r = wv; r < 64; r += 4) {
    float re = xsr[base + r * 64 + lane];
    float im = xsi[base + r * 64 + lane];
    fft64_fwd(re, im, lane);
    lr[r * 65 + lane] = re; li[r * 65 + lane] = im;
  }
  __syncthreads();
  // cols forward
  for (int c = wv; c < 64; c += 4) {
    float re = lr[lane * 65 + c], im = li[lane * 65 + c];
    fft64_fwd(re, im, lane);
    lr[lane * 65 + c] = re; li[lane * 65 + c] = im;
  }
  __syncthreads();
  // rows: multiply by bit-rev-reordered spec, inverse
  for (int r = wv; r < 64; r += 4) {
    float re = lr[r * 65 + lane], im = li[r * 65 + lane];
    float sr = sbr[(size_t)d * NHW + r * 64 + lane];
    float si = sbi[(size_t)d * NHW + r * 64 + lane];
    float nr = re * sr - im * si, ni = re * si + im * sr;
    fft64_inv(nr, ni, lane);
    lr[r * 65 + lane] = nr * (1.0f / 64.0f);
    li[r * 65 + lane] = ni * (1.0f / 64.0f);
  }
  __syncthreads();
  // cols inverse
  for (int c = wv; c < 64; c += 4) {
    float re = lr[lane * 65 + c], im = li[lane * 65 + c];
    fft64_inv(re, im, lane);
    lr[lane * 65 + c] = re * (1.0f / 64.0f);
    li[lane * 65 + c] = im * (1.0f / 64.0f);
  }
  __syncthreads();
  // combine + residual, write back into xs
  for (int r = wv; r < 64; r += 4) {
    size_t off = base + r * 64 + lane;
    float spr = lr[r * 65 + lane], spi = li[r * 65 + lane];
    float outr = g * __bfloat162float(cr[off]) + (1.f - g) * spr + x0r[off];
    float outi = g * __bfloat162float(ci[off]) + (1.f - g) * spi + x0i[off];
    xsr[off] = outr; xsi[off] = outi;
  }
}

// ---------------------------------------------------------------- temporal (fused)
// per block: b fixed, 32 consecutive hw. LN_t -> xE -> scan over T -> xDm(real) -> x_r += drift
__global__ __launch_bounds__(256) void k_temporal(
    float* xsr, const float* xsi,
    const float* __restrict__ lng, const float* __restrict__ lnb,
    const float* __restrict__ lam_r, const float* __restrict__ lam_i,
    const float* __restrict__ dtv,
    const float* __restrict__ er, const float* __restrict__ ei,
    const float* __restrict__ dmr, const float* __restrict__ dmi) {
  __shared__ float ur[64][32], ui[64][32];
  __shared__ float hr[64][32], hi[64][32];
  __shared__ float red_s[8][32], red_ss[8][32];
  __shared__ float decr[64], deci[64], forr[64], fori[64];
  int b = blockIdx.x >> 7;                 // 128 blocks per b
  int hw0 = (blockIdx.x & 127) << 5;
  int tid = threadIdx.x;
  int hwL = tid & 31, q = tid >> 5;        // q 0..7
  if (tid < 64) {
    float lrv = lam_r[tid], liv = lam_i[tid];
    float dtb = dtv[b];
    float mg = __expf(lrv * dtb);
    float s, c;
    __sincosf(liv * dtb, &s, &c);
    float der = mg * c, dei = mg * s;
    float nr = der - 1.0f, ni = dei;
    float dn = 1.0f / (lrv * lrv + liv * liv);
    decr[tid] = der; deci[tid] = dei;
    forr[tid] = (nr * lrv + ni * liv) * dn;
    fori[tid] = (ni * lrv - nr * liv) * dn;
  }
  for (int i = tid; i < 64 * 32; i += 256) { (&hr[0][0])[i] = 0.f; (&hi[0][0])[i] = 0.f; }
  __syncthreads();
  for (int t = 0; t < NT; ++t) {
    size_t base = ((size_t)((b * NT + t) * ND)) * NHW + hw0;
    // load slab
#pragma unroll
    for (int k = 0; k < 8; ++k) {
      int dd = q * 8 + k;
      ur[dd][hwL] = xsr[base + (size_t)dd * NHW + hwL];
      ui[dd][hwL] = xsi[base + (size_t)dd * NHW + hwL];
    }
    __syncthreads();
    // LN partial sums (values q*16 .. q*16+15 of the 128-vector)
    {
      float s0 = 0.f, s1 = 0.f;
#pragma unroll
      for (int k = 0; k < 16; ++k) {
        int v = q * 16 + k;
        float x = (q < 4) ? ur[v][hwL] : ui[v - 64][hwL];
        s0 += x; s1 += x * x;
      }
      red_s[q][hwL] = s0; red_ss[q][hwL] = s1;
    }
    __syncthreads();
    float s = 0.f, ss = 0.f;
#pragma unroll
    for (int k = 0; k < 8; ++k) { s += red_s[k][hwL]; ss += red_ss[k][hwL]; }
    float mean = s * 0.0078125f;
    float rstd = rsqrtf(ss * 0.0078125f - mean * mean + 1e-5f);
#pragma unroll
    for (int k = 0; k < 16; ++k) {
      int v = q * 16 + k;
      if (q < 4) ur[v][hwL] = (ur[v][hwL] - mean) * rstd * lng[v] + lnb[v];
      else       ui[v - 64][hwL] = (ui[v - 64][hwL] - mean) * rstd * lng[v] + lnb[v];
    }
    __syncthreads();
    // eigen projection: this thread owns ed = q*8 .. q*8+7
    float ar[8], ac[8];
#pragma unroll
    for (int j = 0; j < 8; ++j) { ar[j] = 0.f; ac[j] = 0.f; }
    for (int d2 = 0; d2 < 64; ++d2) {
      float xr = ur[d2][hwL], xi2 = ui[d2][hwL];
      float wre[8], wim[8];
      *(float4*)&wre[0] = *(const float4*)(er + d2 * 64 + q * 8);
      *(float4*)&wre[4] = *(const float4*)(er + d2 * 64 + q * 8 + 4);
      *(float4*)&wim[0] = *(const float4*)(ei + d2 * 64 + q * 8);
      *(float4*)&wim[4] = *(const float4*)(ei + d2 * 64 + q * 8 + 4);
#pragma unroll
      for (int j = 0; j < 8; ++j) {
        ar[j] += xr * wre[j] - xi2 * wim[j];
        ac[j] += xr * wim[j] + xi2 * wre[j];
      }
    }
    // recurrence update
#pragma unroll
    for (int j = 0; j < 8; ++j) {
      int ed = q * 8 + j;
      float h0r = hr[ed][hwL], h0i = hi[ed][hwL];
      float nr2 = h0r * decr[ed] - h0i * deci[ed] + ar[j] * forr[ed] - ac[j] * fori[ed];
      float ni2 = h0r * deci[ed] + h0i * decr[ed] + ar[j] * fori[ed] + ac[j] * forr[ed];
      hr[ed][hwL] = nr2; hi[ed][hwL] = ni2;
    }
    __syncthreads();
    // decode (real part) : this thread owns dd = q*8 .. q*8+7
    float da[8];
#pragma unroll
    for (int j = 0; j < 8; ++j) da[j] = 0.f;
    for (int ed = 0; ed < 64; ++ed) {
      float h2r = hr[ed][hwL], h2i = hi[ed][hwL];
      float wre[8], wim[8];
      *(float4*)&wre[0] = *(const float4*)(dmr + ed * 64 + q * 8);
      *(float4*)&wre[4] = *(const float4*)(dmr + ed * 64 + q * 8 + 4);
      *(float4*)&wim[0] = *(const float4*)(dmi + ed * 64 + q * 8);
      *(float4*)&wim[4] = *(const float4*)(dmi + ed * 64 + q * 8 + 4);
#pragma unroll
      for (int j = 0; j < 8; ++j) da[j] += h2r * wre[j] - h2i * wim[j];
    }
#pragma unroll
    for (int j = 0; j < 8; ++j) {
      int dd = q * 8 + j;
      xsr[base + (size_t)dd * NHW + hwL] += da[j];
    }
    __syncthreads();
  }
}

// ---------------------------------------------------------------- channel MLP
// per token (b,t,h,w): f[128]=concat(re,im); h1=gelu(f@W1+b1); out = f + h1@W2+b2
// block: 16 tokens x 256 threads; writes d_out (B,T,2D,H,W) directly.
__global__ __launch_bounds__(256) void k_mlp(
    const float* __restrict__ xsr, const float* __restrict__ xsi,
    const float* __restrict__ w1, const float* __restrict__ b1,
    const float* __restrict__ w2, const float* __restrict__ b2,
    float* __restrict__ out) {
  __shared__ float f[16 * 129];
  __shared__ float h1[512 * 17];
  int blk = blockIdx.x;                 // 16384 = bt*256 + hwtile
  int bt = blk >> 8;
  int hw0 = (blk & 255) << 4;
  int tid = threadIdx.x;
  int tok = tid & 15, gq = tid >> 4;    // gq 0..15
  // load f tile
#pragma unroll
  for (int k = 0; k < 8; ++k) {
    int c = gq + k * 16;
    float v;
    if (c < 64) v = xsr[((size_t)(bt * 64 + c)) * NHW + hw0 + tok];
    else        v = xsi[((size_t)(bt * 64 + c - 64)) * NHW + hw0 + tok];
    f[tok * 129 + c] = v;
  }
  __syncthreads();
  // h1 = gelu(f @ W1 + b1); each thread: 32 cols (gq*32 + jb*8 + j)
  for (int jb = 0; jb < 4; ++jb) {
    int col0 = gq * 32 + jb * 8;
    float acc[8];
#pragma unroll
    for (int j = 0; j < 8; ++j) acc[j] = b1[col0 + j];
    for (int k = 0; k < 128; ++k) {
      float fv = f[tok * 129 + k];
      float4 wa = *(const float4*)(w1 + (size_t)k * 512 + col0);
      float4 wb = *(const float4*)(w1 + (size_t)k * 512 + col0 + 4);
      acc[0] += fv * wa.x; acc[1] += fv * wa.y; acc[2] += fv * wa.z; acc[3] += fv * wa.w;
      acc[4] += fv * wb.x; acc[5] += fv * wb.y; acc[6] += fv * wb.z; acc[7] += fv * wb.w;
    }
#pragma unroll
    for (int j = 0; j < 8; ++j) {
      float x = acc[j];
      float y = 0.7978845608f * (x + 0.044715f * x * x * x);
      float e = __expf(2.0f * y);
      float th = 1.0f - 2.0f / (e + 1.0f);          // tanh(y)
      h1[(col0 + j) * 17 + tok] = 0.5f * x * (1.0f + th);
    }
  }
  __syncthreads();
  // out = f + h1 @ W2 + b2 ; each thread: 8 cols
  int c0 = gq * 8;
  float acc[8];
#pragma unroll
  for (int j = 0; j < 8; ++j) acc[j] = b2[c0 + j];
  for (int k = 0; k < 512; ++k) {
    float hv = h1[k * 17 + tok];
    float4 wa = *(const float4*)(w2 + (size_t)k * 128 + c0);
    float4 wb = *(const float4*)(w2 + (size_t)k * 128 + c0 + 4);
    acc[0] += hv * wa.x; acc[1] += hv * wa.y; acc[2] += hv * wa.z; acc[3] += hv * wa.w;
    acc[4] += hv * wb.x; acc[5] += hv * wb.y; acc[6] += hv * wb.z; acc[7] += hv * wb.w;
  }
#pragma unroll
  for (int j = 0; j < 8; ++j) {
    int c = c0 + j;
    out[((size_t)(bt * 128 + c)) * NHW + hw0 + tok] = f[tok * 129 + c] + acc[j];
  }
}

// ---------------------------------------------------------------- launch
extern "C" void kernel_launch(void* const* d_in, const int* in_sizes, int n_in,
                              void* d_out, int out_size, void* d_ws, size_t ws_size,
                              hipStream_t stream) {
  const float* x_r    = (const float*)d_in[0];
  const float* x_i    = (const float*)d_in[1];
  const float* dt     = (const float*)d_in[2];
  const float* ln_s_g = (const float*)d_in[3];
  const float* ln_s_b = (const float*)d_in[4];
  const float* conv_w = (const float*)d_in[5];
  const float* conv_b = (const float*)d_in[6];
  const float* spec_wr= (const float*)d_in[7];
  const float* spec_wi= (const float*)d_in[8];
  const float* gate   = (const float*)d_in[9];
  const float* ln_t_g = (const float*)d_in[10];
  const float* ln_t_b = (const float*)d_in[11];
  const float* lam_r  = (const float*)d_in[12];
  const float* lam_i  = (const float*)d_in[13];
  const float* enc_r  = (const float*)d_in[14];
  const float* enc_i  = (const float*)d_in[15];
  const float* dec_r  = (const float*)d_in[16];
  const float* dec_i  = (const float*)d_in[17];
  const float* p_w1   = (const float*)d_in[18];
  const float* p_b1   = (const float*)d_in[19];
  const float* p_w2   = (const float*)d_in[20];
  const float* p_b2   = (const float*)d_in[21];

  float* ws   = (float*)d_ws;
  float* xs_r = ws;                       // N fp32
  float* xs_i = ws + (size_t)NTOT;        // N fp32
  float* sbr  = ws + (size_t)2 * NTOT;    // D*HW fp32
  float* sbi  = sbr + (size_t)ND * NHW;
  __hip_bfloat16* cl_r = (__hip_bfloat16*)(sbi + (size_t)ND * NHW);  // N bf16
  __hip_bfloat16* cl_i = cl_r + (size_t)NTOT;                        // N bf16

  k_spec_reorder<<<1024, 256, 0, stream>>>(spec_wr, spec_wi, sbr, sbi);
  k_ln<<<1024, 256, 0, stream>>>(x_r, x_i, ln_s_g, ln_s_b, xs_r, xs_i);
  k_conv<<<4096, 256, 0, stream>>>(xs_r, xs_i, conv_w, conv_b, cl_r, cl_i);
  k_fft_combine<<<4096, 256, 0, stream>>>(xs_r, xs_i, cl_r, cl_i, sbr, sbi, x_r, x_i, gate);
  k_temporal<<<512, 256, 0, stream>>>(xs_r, xs_i, ln_t_g, ln_t_b, lam_r, lam_i, dt,
                                      enc_r, enc_i, dec_r, dec_i);
  k_mlp<<<16384, 256, 0, stream>>>(xs_r, xs_i, p_w1, p_b1, p_w2, p_b2, (float*)d_out);
}

// Round 2
// 2436.561 us; speedup vs baseline: 2.4502x; 2.4502x over previous
//
#include <hip/hip_runtime.h>
#include <hip/hip_bf16.h>

#define NB 4
#define NT 16
#define ND 64
#define NHW 4096
#define NTOT (NB*NT*ND*NHW)   // 16,777,216 per plane

typedef __attribute__((ext_vector_type(8))) __bf16 bf16x8;
typedef __attribute__((ext_vector_type(4))) float f32x4;

// ---------------------------------------------------------------- spec reorder
__global__ void k_spec_reorder(const float* __restrict__ wr, const float* __restrict__ wi,
                               float* __restrict__ outr, float* __restrict__ outi) {
  int idx = blockIdx.x * 256 + threadIdx.x;      // D*HW = 262144
  int d = idx >> 12;
  int rc = idx & 4095;
  int r = rc >> 6, c = rc & 63;
  int br = __brev((unsigned)r) >> 26;
  int bc = __brev((unsigned)c) >> 26;
  int src = (d << 12) + (br << 6) + bc;
  outr[idx] = wr[src];
  outi[idx] = wi[src];
}

// ---------------------------------------------------------------- complex LN
__global__ void k_ln(const float* __restrict__ xr, const float* __restrict__ xi,
                     const float* __restrict__ g, const float* __restrict__ b,
                     float* __restrict__ outr, float* __restrict__ outi) {
  int pos = blockIdx.x * 256 + threadIdx.x;      // B*T*HW = 262144
  int bt = pos >> 12;
  int hw = pos & 4095;
  size_t base = (size_t)bt * ND * NHW + hw;
  float s = 0.f, ss = 0.f;
  for (int d = 0; d < ND; ++d) {
    float r = xr[base + (size_t)d * NHW];
    float im = xi[base + (size_t)d * NHW];
    s += r + im; ss += r * r + im * im;
  }
  float mean = s * (1.0f / 128.0f);
  float var = ss * (1.0f / 128.0f) - mean * mean;
  float rstd = rsqrtf(var + 1e-5f);
  for (int d = 0; d < ND; ++d) {
    float r = xr[base + (size_t)d * NHW];
    float im = xi[base + (size_t)d * NHW];
    outr[base + (size_t)d * NHW] = (r - mean) * rstd * g[d] + b[d];
    outi[base + (size_t)d * NHW] = (im - mean) * rstd * g[64 + d] + b[64 + d];
  }
}

// ---------------------------------------------------------------- 3x3 conv
__global__ __launch_bounds__(256) void k_conv(
    const float* __restrict__ xsr, const float* __restrict__ xsi,
    const float* __restrict__ w, const float* __restrict__ bias,
    __hip_bfloat16* __restrict__ cr, __hip_bfloat16* __restrict__ ci) {
  __shared__ float tin[18 * 34];
  __shared__ float tw2[9 * 16];     // [k][o]
  int blk = blockIdx.x;             // bt*64 + ocg*8 + tile
  int tile = blk & 7;
  int ocg = (blk >> 3) & 7;
  int bt = blk >> 6;
  int ty0 = (tile >> 1) * 16, tx0 = (tile & 1) * 32;
  int tid = threadIdx.x;
  int px = tid & 15, py = tid >> 4;
  float acc0[16], acc1[16];
#pragma unroll
  for (int o = 0; o < 16; ++o) { float bz = bias[ocg * 16 + o]; acc0[o] = bz; acc1[o] = bz; }
  for (int ic = 0; ic < 128; ++ic) {
    const float* src = (ic < 64) ? xsr : xsi;
    size_t sb = ((size_t)(bt * 64 + (ic & 63))) * NHW;
    for (int i = tid; i < 612; i += 256) {
      int iy = i / 34, ix = i - iy * 34;
      int gy = ty0 + iy - 1, gx = tx0 + ix - 1;
      float v = 0.0f;
      if (gy >= 0 && gy < 64 && gx >= 0 && gx < 64) v = src[sb + gy * 64 + gx];
      tin[i] = v;
    }
    if (tid < 144) {
      int o = tid / 9, kk = tid - o * 9;
      tw2[kk * 16 + o] = w[((size_t)(ocg * 16 + o) * 128 + ic) * 9 + kk];
    }
    __syncthreads();
#pragma unroll
    for (int ky = 0; ky < 3; ++ky) {
#pragma unroll
      for (int kx = 0; kx < 3; ++kx) {
        float v0 = tin[(py + ky) * 34 + px + kx];
        float v1 = tin[(py + ky) * 34 + px + 16 + kx];
        int kk = ky * 3 + kx;
#pragma unroll
        for (int o = 0; o < 16; ++o) {
          float wv = tw2[kk * 16 + o];
          acc0[o] += v0 * wv; acc1[o] += v1 * wv;
        }
      }
    }
    __syncthreads();
  }
  int oc0 = ocg * 16;
#pragma unroll
  for (int o = 0; o < 16; ++o) {
    int oc = oc0 + o;
    __hip_bfloat16* dst = (oc < 64) ? cr : ci;
    size_t ob = ((size_t)(bt * 64 + (oc & 63))) * NHW + (ty0 + py) * 64 + tx0;
    dst[ob + px] = __float2bfloat16(acc0[o]);
    dst[ob + px + 16] = __float2bfloat16(acc1[o]);
  }
}

// ---------------------------------------------------------------- FFT64 via shfl
__device__ __forceinline__ void fft64_fwd(float& re, float& im, int lane) {
#pragma unroll
  for (int m = 32; m >= 1; m >>= 1) {
    float pr = __shfl_xor(re, m, 64);
    float pi = __shfl_xor(im, m, 64);
    int j = lane & (m - 1);
    float ang = -3.14159265358979f * (float)j / (float)m;
    float s, c;
    __sincosf(ang, &s, &c);
    if (lane & m) {
      float tr = pr - re, ti = pi - im;
      re = tr * c - ti * s;
      im = tr * s + ti * c;
    } else { re += pr; im += pi; }
  }
}
__device__ __forceinline__ void fft64_inv(float& re, float& im, int lane) {
#pragma unroll
  for (int m = 1; m <= 32; m <<= 1) {
    int j = lane & (m - 1);
    float ang = 3.14159265358979f * (float)j / (float)m;
    float s, c;
    __sincosf(ang, &s, &c);
    float pr = __shfl_xor(re, m, 64);
    float pi = __shfl_xor(im, m, 64);
    if (lane & m) {
      float wr = re * c - im * s, wi = re * s + im * c;
      re = pr - wr; im = pi - wi;
    } else {
      float wr = pr * c - pi * s, wi = pr * s + pi * c;
      re += wr; im += wi;
    }
  }
}

__global__ __launch_bounds__(256) void k_fft_combine(
    float* xsr, float* xsi,
    const __hip_bfloat16* __restrict__ cr, const __hip_bfloat16* __restrict__ ci,
    const float* __restrict__ sbr, const float* __restrict__ sbi,
    const float* __restrict__ x0r, const float* __restrict__ x0i,
    const float* __restrict__ gate) {
  __shared__ float lr[64 * 65], li[64 * 65];
  int slice = blockIdx.x;                      // bt*64 + d
  int d = slice & 63;
  size_t base = (size_t)slice * NHW;
  int lane = threadIdx.x & 63, wv = threadIdx.x >> 6;
  float g = gate[0];
  for (int r = wv; r < 64; r += 4) {
    float re = xsr[base + r * 64 + lane];
    float im = xsi[base + r * 64 + lane];
    fft64_fwd(re, im, lane);
    lr[r * 65 + lane] = re; li[r * 65 + lane] = im;
  }
  __syncthreads();
  for (int c = wv; c < 64; c += 4) {
    float re = lr[lane * 65 + c], im = li[lane * 65 + c];
    fft64_fwd(re, im, lane);
    lr[lane * 65 + c] = re; li[lane * 65 + c] = im;
  }
  __syncthreads();
  for (int r = wv; r < 64; r += 4) {
    float re = lr[r * 65 + lane], im = li[r * 65 + lane];
    float sr = sbr[(size_t)d * NHW + r * 64 + lane];
    float si = sbi[(size_t)d * NHW + r * 64 + lane];
    float nr = re * sr - im * si, ni = re * si + im * sr;
    fft64_inv(nr, ni, lane);
    lr[r * 65 + lane] = nr * (1.0f / 64.0f);
    li[r * 65 + lane] = ni * (1.0f / 64.0f);
  }
  __syncthreads();
  for (int c = wv; c < 64; c += 4) {
    float re = lr[lane * 65 + c], im = li[lane * 65 + c];
    fft64_inv(re, im, lane);
    lr[lane * 65 + c] = re * (1.0f / 64.0f);
    li[lane * 65 + c] = im * (1.0f / 64.0f);
  }
  __syncthreads();
  for (int r = wv; r < 64; r += 4) {
    size_t off = base + r * 64 + lane;
    float spr = lr[r * 65 + lane], spi = li[r * 65 + lane];
    float outr = g * __bfloat162float(cr[off]) + (1.f - g) * spr + x0r[off];
    float outi = g * __bfloat162float(ci[off]) + (1.f - g) * spi + x0i[off];
    xsr[off] = outr; xsi[off] = outi;
  }
}

// ---------------------------------------------------------------- temporal (fused)
__global__ __launch_bounds__(256) void k_temporal(
    float* xsr, const float* xsi,
    const float* __restrict__ lng, const float* __restrict__ lnb,
    const float* __restrict__ lam_r, const float* __restrict__ lam_i,
    const float* __restrict__ dtv,
    const float* __restrict__ er, const float* __restrict__ ei,
    const float* __restrict__ dmr, const float* __restrict__ dmi) {
  __shared__ float ur[64][32], ui[64][32];
  __shared__ float hr[64][32], hi[64][32];
  __shared__ float red_s[8][32], red_ss[8][32];
  __shared__ float decr[64], deci[64], forr[64], fori[64];
  int b = blockIdx.x >> 7;
  int hw0 = (blockIdx.x & 127) << 5;
  int tid = threadIdx.x;
  int hwL = tid & 31, q = tid >> 5;
  if (tid < 64) {
    float lrv = lam_r[tid], liv = lam_i[tid];
    float dtb = dtv[b];
    float mg = __expf(lrv * dtb);
    float s, c;
    __sincosf(liv * dtb, &s, &c);
    float der = mg * c, dei = mg * s;
    float nr = der - 1.0f, ni = dei;
    float dn = 1.0f / (lrv * lrv + liv * liv);
    decr[tid] = der; deci[tid] = dei;
    forr[tid] = (nr * lrv + ni * liv) * dn;
    fori[tid] = (ni * lrv - nr * liv) * dn;
  }
  for (int i = tid; i < 64 * 32; i += 256) { (&hr[0][0])[i] = 0.f; (&hi[0][0])[i] = 0.f; }
  __syncthreads();
  for (int t = 0; t < NT; ++t) {
    size_t base = ((size_t)((b * NT + t) * ND)) * NHW + hw0;
#pragma unroll
    for (int k = 0; k < 8; ++k) {
      int dd = q * 8 + k;
      ur[dd][hwL] = xsr[base + (size_t)dd * NHW + hwL];
      ui[dd][hwL] = xsi[base + (size_t)dd * NHW + hwL];
    }
    __syncthreads();
    {
      float s0 = 0.f, s1 = 0.f;
#pragma unroll
      for (int k = 0; k < 16; ++k) {
        int v = q * 16 + k;
        float x = (q < 4) ? ur[v][hwL] : ui[v - 64][hwL];
        s0 += x; s1 += x * x;
      }
      red_s[q][hwL] = s0; red_ss[q][hwL] = s1;
    }
    __syncthreads();
    float s = 0.f, ss = 0.f;
#pragma unroll
    for (int k = 0; k < 8; ++k) { s += red_s[k][hwL]; ss += red_ss[k][hwL]; }
    float mean = s * 0.0078125f;
    float rstd = rsqrtf(ss * 0.0078125f - mean * mean + 1e-5f);
#pragma unroll
    for (int k = 0; k < 16; ++k) {
      int v = q * 16 + k;
      if (q < 4) ur[v][hwL] = (ur[v][hwL] - mean) * rstd * lng[v] + lnb[v];
      else       ui[v - 64][hwL] = (ui[v - 64][hwL] - mean) * rstd * lng[v] + lnb[v];
    }
    __syncthreads();
    float ar[8], ac[8];
#pragma unroll
    for (int j = 0; j < 8; ++j) { ar[j] = 0.f; ac[j] = 0.f; }
    for (int d2 = 0; d2 < 64; ++d2) {
      float xr = ur[d2][hwL], xi2 = ui[d2][hwL];
      float wre[8], wim[8];
      *(float4*)&wre[0] = *(const float4*)(er + d2 * 64 + q * 8);
      *(float4*)&wre[4] = *(const float4*)(er + d2 * 64 + q * 8 + 4);
      *(float4*)&wim[0] = *(const float4*)(ei + d2 * 64 + q * 8);
      *(float4*)&wim[4] = *(const float4*)(ei + d2 * 64 + q * 8 + 4);
#pragma unroll
      for (int j = 0; j < 8; ++j) {
        ar[j] += xr * wre[j] - xi2 * wim[j];
        ac[j] += xr * wim[j] + xi2 * wre[j];
      }
    }
#pragma unroll
    for (int j = 0; j < 8; ++j) {
      int ed = q * 8 + j;
      float h0r = hr[ed][hwL], h0i = hi[ed][hwL];
      float nr2 = h0r * decr[ed] - h0i * deci[ed] + ar[j] * forr[ed] - ac[j] * fori[ed];
      float ni2 = h0r * deci[ed] + h0i * decr[ed] + ar[j] * fori[ed] + ac[j] * forr[ed];
      hr[ed][hwL] = nr2; hi[ed][hwL] = ni2;
    }
    __syncthreads();
    float da[8];
#pragma unroll
    for (int j = 0; j < 8; ++j) da[j] = 0.f;
    for (int ed = 0; ed < 64; ++ed) {
      float h2r = hr[ed][hwL], h2i = hi[ed][hwL];
      float wre[8], wim[8];
      *(float4*)&wre[0] = *(const float4*)(dmr + ed * 64 + q * 8);
      *(float4*)&wre[4] = *(const float4*)(dmr + ed * 64 + q * 8 + 4);
      *(float4*)&wim[0] = *(const float4*)(dmi + ed * 64 + q * 8);
      *(float4*)&wim[4] = *(const float4*)(dmi + ed * 64 + q * 8 + 4);
#pragma unroll
      for (int j = 0; j < 8; ++j) da[j] += h2r * wre[j] - h2i * wim[j];
    }
#pragma unroll
    for (int j = 0; j < 8; ++j) {
      int dd = q * 8 + j;
      xsr[base + (size_t)dd * NHW + hwL] += da[j];
    }
    __syncthreads();
  }
}

// ---------------------------------------------------------------- weight repack (bf16, MFMA B-fragment order)
// W1p[((nt*4+kt)*64+lane)*8+j] = W1[kt*32+(lane>>4)*8+j][nt*16+(lane&15)]   (nt<32,kt<4)
// W2p[((nt*16+kt)*64+lane)*8+j] = W2[kt*32+(lane>>4)*8+j][nt*16+(lane&15)]  (nt<8,kt<16)
__global__ void k_repack(const float* __restrict__ w1, const float* __restrict__ w2,
                         __hip_bfloat16* __restrict__ w1p, __hip_bfloat16* __restrict__ w2p) {
  int idx = blockIdx.x * 256 + threadIdx.x;   // 131072
  if (idx < 65536) {
    int j = idx & 7, lane = (idx >> 3) & 63, kt = (idx >> 9) & 3, nt = idx >> 11;
    int k = kt * 32 + (lane >> 4) * 8 + j;
    int n = nt * 16 + (lane & 15);
    w1p[idx] = __float2bfloat16(w1[k * 512 + n]);
  } else {
    int i2 = idx - 65536;
    int j = i2 & 7, lane = (i2 >> 3) & 63, kt = (i2 >> 9) & 15, nt = i2 >> 13;
    int k = kt * 32 + (lane >> 4) * 8 + j;
    int n = nt * 16 + (lane & 15);
    w2p[i2] = __float2bfloat16(w2[k * 128 + n]);
  }
}

// ---------------------------------------------------------------- channel MLP via MFMA
// block: 32 tokens, 256 thr (4 waves). GEMM1(32x128 @ 128x512) -> gelu -> GEMM2(32x512 @ 512x128)
__global__ __launch_bounds__(256, 3) void k_mlp_mfma(
    const float* __restrict__ xsr, const float* __restrict__ xsi,
    const __hip_bfloat16* __restrict__ w1p, const __hip_bfloat16* __restrict__ w2p,
    const float* __restrict__ b1, const float* __restrict__ b2,
    float* __restrict__ out) {
  __shared__ __bf16 lf[32 * 136];          // f bf16, row stride 136
  __shared__ __bf16 lh[32 * 520];          // h1 bf16, row stride 520 (reused as fp32 out[128][33])
  float* lo = (float*)lh;
  int blk = blockIdx.x;                    // 8192 = bt*128 + hwtile
  int bt = blk >> 7;
  int hw0 = (blk & 127) << 5;
  int tid = threadIdx.x;
  int lane = tid & 63, wave = tid >> 6;
  int lc = lane & 15, quad = lane >> 4;
  // ---- stage f (fp32 global -> bf16 LDS) ----
  {
    int tok = tid & 31, cg = tid >> 5;
#pragma unroll
    for (int it = 0; it < 16; ++it) {
      int c = it * 8 + cg;
      const float* src = (c < 64) ? (xsr + ((size_t)(bt * 64 + c)) * NHW)
                                  : (xsi + ((size_t)(bt * 64 + c - 64)) * NHW);
      lf[tok * 136 + c] = (__bf16)src[hw0 + tok];
    }
  }
  __syncthreads();
  // ---- GEMM1: h1[32][512], wave owns cols wave*128..+127 ----
  f32x4 acc[2][8];
#pragma unroll
  for (int mt = 0; mt < 2; ++mt)
#pragma unroll
    for (int nt = 0; nt < 8; ++nt) acc[mt][nt] = (f32x4){0.f, 0.f, 0.f, 0.f};
#pragma unroll
  for (int kt = 0; kt < 4; ++kt) {
    bf16x8 a0 = *(const bf16x8*)&lf[lc * 136 + kt * 32 + quad * 8];
    bf16x8 a1 = *(const bf16x8*)&lf[(lc + 16) * 136 + kt * 32 + quad * 8];
    const __hip_bfloat16* wp = w1p + (((size_t)(wave * 8) * 4 + kt) * 64 + lane) * 8;
#pragma unroll
    for (int nt = 0; nt < 8; ++nt) {
      bf16x8 b = *(const bf16x8*)(const void*)(wp + (size_t)nt * (4 * 64 * 8));
      acc[0][nt] = __builtin_amdgcn_mfma_f32_16x16x32_bf16(a0, b, acc[0][nt], 0, 0, 0);
      acc[1][nt] = __builtin_amdgcn_mfma_f32_16x16x32_bf16(a1, b, acc[1][nt], 0, 0, 0);
    }
  }
  // ---- gelu -> lh (bf16) ----
#pragma unroll
  for (int nt = 0; nt < 8; ++nt) {
    int col = wave * 128 + nt * 16 + lc;
    float bb = b1[col];
#pragma unroll
    for (int mt = 0; mt < 2; ++mt)
#pragma unroll
      for (int r = 0; r < 4; ++r) {
        float x = acc[mt][nt][r] + bb;
        float y = 0.7978845608f * (x + 0.044715f * x * x * x);
        float e = __expf(2.0f * y);
        float th = 1.0f - 2.0f / (e + 1.0f);
        float gv = 0.5f * x * (1.0f + th);
        lh[(mt * 16 + quad * 4 + r) * 520 + col] = (__bf16)gv;
      }
  }
  __syncthreads();
  // ---- GEMM2: out[32][128], wave owns cols wave*32..+31 ----
  f32x4 acc2[2][2];
#pragma unroll
  for (int mt = 0; mt < 2; ++mt)
#pragma unroll
    for (int n = 0; n < 2; ++n) acc2[mt][n] = (f32x4){0.f, 0.f, 0.f, 0.f};
#pragma unroll
  for (int kt = 0; kt < 16; ++kt) {
    bf16x8 a0 = *(const bf16x8*)&lh[lc * 520 + kt * 32 + quad * 8];
    bf16x8 a1 = *(const bf16x8*)&lh[(lc + 16) * 520 + kt * 32 + quad * 8];
#pragma unroll
    for (int n = 0; n < 2; ++n) {
      bf16x8 b = *(const bf16x8*)(const void*)(w2p + (((size_t)(wave * 2 + n) * 16 + kt) * 64 + lane) * 8);
      acc2[0][n] = __builtin_amdgcn_mfma_f32_16x16x32_bf16(a0, b, acc2[0][n], 0, 0, 0);
      acc2[1][n] = __builtin_amdgcn_mfma_f32_16x16x32_bf16(a1, b, acc2[1][n], 0, 0, 0);
    }
  }
  __syncthreads();   // all lh reads done; reuse as fp32 out staging
  // ---- epilogue: acc2 + b2 -> lo[c][tok] ----
#pragma unroll
  for (int n = 0; n < 2; ++n) {
    int c = wave * 32 + n * 16 + lc;
    float bb = b2[c];
#pragma unroll
    for (int mt = 0; mt < 2; ++mt)
#pragma unroll
      for (int r = 0; r < 4; ++r)
        lo[c * 33 + mt * 16 + quad * 4 + r] = acc2[mt][n][r] + bb;
  }
  __syncthreads();
  // ---- final: out = lo + f_resid (fp32), coalesced ----
  {
    int tok = tid & 31, cg = tid >> 5;
#pragma unroll
    for (int it = 0; it < 16; ++it) {
      int c = it * 8 + cg;
      const float* src = (c < 64) ? (xsr + ((size_t)(bt * 64 + c)) * NHW)
                                  : (xsi + ((size_t)(bt * 64 + c - 64)) * NHW);
      out[((size_t)(bt * 128 + c)) * NHW + hw0 + tok] = lo[c * 33 + tok] + src[hw0 + tok];
    }
  }
}

// ---------------------------------------------------------------- launch
extern "C" void kernel_launch(void* const* d_in, const int* in_sizes, int n_in,
                              void* d_out, int out_size, void* d_ws, size_t ws_size,
                              hipStream_t stream) {
  const float* x_r    = (const float*)d_in[0];
  const float* x_i    = (const float*)d_in[1];
  const float* dt     = (const float*)d_in[2];
  const float* ln_s_g = (const float*)d_in[3];
  const float* ln_s_b = (const float*)d_in[4];
  const float* conv_w = (const float*)d_in[5];
  const float* conv_b = (const float*)d_in[6];
  const float* spec_wr= (const float*)d_in[7];
  const float* spec_wi= (const float*)d_in[8];
  const float* gate   = (const float*)d_in[9];
  const float* ln_t_g = (const float*)d_in[10];
  const float* ln_t_b = (const float*)d_in[11];
  const float* lam_r  = (const float*)d_in[12];
  const float* lam_i  = (const float*)d_in[13];
  const float* enc_r  = (const float*)d_in[14];
  const float* enc_i  = (const float*)d_in[15];
  const float* dec_r  = (const float*)d_in[16];
  const float* dec_i  = (const float*)d_in[17];
  const float* p_w1   = (const float*)d_in[18];
  const float* p_b1   = (const float*)d_in[19];
  const float* p_w2   = (const float*)d_in[20];
  const float* p_b2   = (const float*)d_in[21];

  float* ws   = (float*)d_ws;
  float* xs_r = ws;                       // N fp32
  float* xs_i = ws + (size_t)NTOT;        // N fp32
  float* sbr  = ws + (size_t)2 * NTOT;    // D*HW fp32
  float* sbi  = sbr + (size_t)ND * NHW;
  __hip_bfloat16* cl_r = (__hip_bfloat16*)(sbi + (size_t)ND * NHW);  // N bf16
  __hip_bfloat16* cl_i = cl_r + (size_t)NTOT;                        // N bf16
  // repacked weights overlap cl_r region (conv outputs dead after k_fft_combine)
  __hip_bfloat16* w1p = cl_r;             // 65536 bf16
  __hip_bfloat16* w2p = w1p + 65536;      // 65536 bf16

  k_spec_reorder<<<1024, 256, 0, stream>>>(spec_wr, spec_wi, sbr, sbi);
  k_ln<<<1024, 256, 0, stream>>>(x_r, x_i, ln_s_g, ln_s_b, xs_r, xs_i);
  k_conv<<<4096, 256, 0, stream>>>(xs_r, xs_i, conv_w, conv_b, cl_r, cl_i);
  k_fft_combine<<<4096, 256, 0, stream>>>(xs_r, xs_i, cl_r, cl_i, sbr, sbi, x_r, x_i, gate);
  k_repack<<<512, 256, 0, stream>>>(p_w1, p_w2, w1p, w2p);
  k_temporal<<<512, 256, 0, stream>>>(xs_r, xs_i, ln_t_g, ln_t_b, lam_r, lam_i, dt,
                                      enc_r, enc_i, dec_r, dec_i);
  k_mlp_mfma<<<8192, 256, 0, stream>>>(xs_r, xs_i, w1p, w2p, p_b1, p_b2, (float*)d_out);
}